// Round 1
// baseline (114.147 us; speedup 1.0000x reference)
//
#include <hip/hip_runtime.h>

typedef __attribute__((ext_vector_type(8))) short short8;
typedef __attribute__((ext_vector_type(4))) float f32x4;

#define IN_DIM 256
#define OUT_DIM 256
#define NB 16                 // padded basis count (13 real + 3 zero)
#define KDIM (IN_DIM * NB)    // 4096
#define TM 128
#define TN 128
#define BK 64                 // 4 i-values per K-step
#define KSPLIT 4
#define IPER (IN_DIM / KSPLIT)   // 64 i-values per block
#define STEPS (IPER / 4)         // 16

__device__ __forceinline__ unsigned short f2bf(float f) {
  union { float f; unsigned int u; } v; v.f = f;
  unsigned int r = v.u + 0x7fffu + ((v.u >> 16) & 1u);  // RNE
  return (unsigned short)(r >> 16);
}

// async global->LDS, 16 B per lane, linear wave dest (base + lane*16)
__device__ __forceinline__ void glds16(const void* g, void* l) {
  __builtin_amdgcn_global_load_lds((__attribute__((address_space(1))) const void*)g,
                                   (__attribute__((address_space(3))) void*)l, 16, 0, 0);
}

// branchless cubic B-spline row: 16 bf16 slots (packed into d[8] u32), 4 nonzeros at c..c+3
__device__ __forceinline__ void spline_row(float xv, unsigned* d) {
  float xc = fminf(fmaxf(xv, -1.0f), 1.0f - 1e-6f);
  float u = (xc + 1.0f) * 5.0f;            // h = 0.2
  int c = (int)u;
  c = c > 9 ? 9 : (c < 0 ? 0 : c);
  float tt = u - (float)c;
  float omt = 1.0f - tt;
  float t2 = tt * tt, t3 = t2 * tt;
  float b0 = omt * omt * omt * (1.0f / 6.0f);
  float b1 = (3.0f * t3 - 6.0f * t2 + 4.0f) * (1.0f / 6.0f);
  float b2 = (-3.0f * t3 + 3.0f * t2 + 3.0f * tt + 1.0f) * (1.0f / 6.0f);
  float b3 = t3 * (1.0f / 6.0f);
  unsigned h0 = f2bf(b0), h1 = f2bf(b1), h2 = f2bf(b2), h3 = f2bf(b3);
  const int a = c >> 1;
  const bool odd = (c & 1) != 0;
  unsigned p01 = h0 | (h1 << 16);
  unsigned p23 = h2 | (h3 << 16);
  unsigned A0 = odd ? (h0 << 16) : p01;
  unsigned A1 = odd ? (h1 | (h2 << 16)) : p23;
  unsigned A2 = odd ? h3 : 0u;
#pragma unroll
  for (int j = 0; j < 8; ++j) {
    unsigned v = (j == a) ? A0 : 0u;
    v = (j == a + 1) ? A1 : v;
    v = (j == a + 2) ? A2 : v;
    d[j] = v;
  }
}

// --- prep: BmT[o][i*16+n] = bf16( sum_e softmax(gating[i,o,:])[e] * coeff[e,n] ); also zeroes out
__global__ __launch_bounds__(256) void kan_prep(const float* __restrict__ coeff,
                                                const float* __restrict__ gw,
                                                unsigned short* __restrict__ BmT,
                                                float* __restrict__ out) {
  __shared__ float csh[104];
  __shared__ unsigned short tile[16][256];   // [o_loc][il*16+n]
  const int t = threadIdx.x;
  // zero the output (atomic split-K needs zeros); coalesced f4 stores
  {
    const int bid = blockIdx.y * 16 + blockIdx.x;
    float4 z; z.x = z.y = z.z = z.w = 0.f;
    float4* ob = (float4*)out;
#pragma unroll
    for (int j = 0; j < 8; ++j) ob[(size_t)bid * 2048 + j * 256 + t] = z;
  }
  if (t < 104) csh[t] = coeff[t];
  __syncthreads();
  const int otile = blockIdx.x, itile = blockIdx.y;
  const int il = t >> 4, ol = t & 15;
  const int i = itile * 16 + il;
  const int o = otile * 16 + ol;
  const float* g = gw + (size_t)(i * OUT_DIM + o) * 8;
  float4 g0 = *(const float4*)g;
  float4 g1 = *(const float4*)(g + 4);
  float ge[8] = {g0.x, g0.y, g0.z, g0.w, g1.x, g1.y, g1.z, g1.w};
  float mx = ge[0];
#pragma unroll
  for (int e = 1; e < 8; ++e) mx = fmaxf(mx, ge[e]);
  float p[8]; float s = 0.f;
#pragma unroll
  for (int e = 0; e < 8; ++e) { p[e] = __expf(ge[e] - mx); s += p[e]; }
  const float inv = 1.0f / s;
  unsigned short row[16];
#pragma unroll
  for (int n = 0; n < 13; ++n) {
    float w = 0.f;
#pragma unroll
    for (int e = 0; e < 8; ++e) w += p[e] * csh[e * 13 + n];
    row[n] = f2bf(w * inv);
  }
  row[13] = 0; row[14] = 0; row[15] = 0;
  int4* dst = (int4*)&tile[ol][il * 16];
  dst[0] = *(const int4*)&row[0];
  dst[1] = *(const int4*)&row[8];
  __syncthreads();
  const int oo = t >> 4, ck = t & 15;
  int4 v0 = *(const int4*)&tile[oo][ck * 16];
  int4 v1 = *(const int4*)&tile[oo][ck * 16 + 8];
  int4* out4 = (int4*)(BmT + (size_t)(otile * 16 + oo) * KDIM + itile * 256 + ck * 16);
  out4[0] = v0;
  out4[1] = v1;
}

// spline-stage one step's A tile (2 i-values per thread) into swizzled LDS buf
#define STAGE_A(snext, buf) do {                                                   \
    const int p_ = (snext) & 1, h_ = ((snext) >> 1) & 1;                           \
    const char* xb_ = (const char*)&Xsh[0][0] + h_ * 4096;                         \
    float2 xv_ = *(const float2*)(xb_ + r * 32 + ((p_ ^ (r & 1)) << 4) + ph * 8);  \
    char* ab_ = (char*)&Ash[0][0] + (buf) * 16384 + r * 128;                       \
    const int m_ = r & 7;                                                          \
    unsigned d_[8];                                                                \
    spline_row(xv_.x, d_);                                                         \
    *(int4*)(ab_ + (((4 * ph + 0) ^ m_) << 4)) = *(const int4*)&d_[0];             \
    *(int4*)(ab_ + (((4 * ph + 1) ^ m_) << 4)) = *(const int4*)&d_[4];             \
    spline_row(xv_.y, d_);                                                         \
    *(int4*)(ab_ + (((4 * ph + 2) ^ m_) << 4)) = *(const int4*)&d_[0];             \
    *(int4*)(ab_ + (((4 * ph + 3) ^ m_) << 4)) = *(const int4*)&d_[4];             \
  } while (0)

// --- fused basis + GEMM: out[m][o] += A[m][k] * BmT[o][k], k = i*16+n
// XOR-swizzled unpadded LDS tiles (byte ^= (row&7)<<4, 16B granules).
// B and x staged via global_load_lds (linear dest, inverse-swizzled per-lane source).
// A staged by in-register spline eval writing straight to swizzled LDS.
// One barrier/step, double-buffered; 73728 B LDS -> 2 blocks/CU.
__global__ __launch_bounds__(256, 2) void kan_gemm(const float* __restrict__ x,
                                                   const unsigned short* __restrict__ BmT,
                                                   float* __restrict__ out) {
  __shared__ unsigned short Ash[2][TM * BK];   // 32768 B, swizzled [row][64k]
  __shared__ unsigned short Bsh[2][TN * BK];   // 32768 B, swizzled [o][64k]
  __shared__ float Xsh[2][TM * 8];             // 8192 B, [row][8 i] per half (2 steps)

  const int t = threadIdx.x;
  const int lane = t & 63;
  const int wave = t >> 6;
  const int wm = wave & 1, wn = wave >> 1;       // 2x2 waves, 64x64 each
  const int mb = blockIdx.x * TM;
  const int ob = blockIdx.y * TN;
  const int i0 = blockIdx.z * IPER;

  // A-stager mapping: thread = (row r, i-pair ph)
  const int r = t & 127;
  const int ph = t >> 7;

  // B gload: thread t covers LDS linear bytes q*4096 + t*16
  //   -> row = q*32 + (t>>3), swizzled slot = t&7 holds global chunk (t&7)^((t>>3)&7)
  const int jsw = (t & 7) ^ ((t >> 3) & 7);
  const unsigned short* bgbase = BmT + (size_t)(ob + (t >> 3)) * KDIM + i0 * NB + jsw * 8;
  // x gload: row = t>>1 (32 B rows), chunk (t&1) holds global chunk (t&1)^((t>>1)&1)
  const int csw = (t & 1) ^ ((t >> 1) & 1);
  const float* xgbase = x + (size_t)(mb + (t >> 1)) * IN_DIM + i0 + csw * 4;

  char* const bl = (char*)&Bsh[0][0] + wave * 1024;
  char* const xl = (char*)&Xsh[0][0] + wave * 1024;

  f32x4 acc[4][4];
#pragma unroll
  for (int a = 0; a < 4; ++a)
#pragma unroll
    for (int b = 0; b < 4; ++b) acc[a][b] = (f32x4){0.f, 0.f, 0.f, 0.f};

  // swizzled fragment read offsets (kc=0); kc=1 is ^64 (slot+4 under XOR)
  int aoff[4], boff[4];
#pragma unroll
  for (int f = 0; f < 4; ++f) {
    const int ro = wm * 64 + f * 16 + (lane & 15);
    aoff[f] = ro * 128 + ((((lane >> 4)) ^ (ro & 7)) << 4);
    const int bo = wn * 64 + f * 16 + (lane & 15);
    boff[f] = bo * 128 + ((((lane >> 4)) ^ (bo & 7)) << 4);
  }

  // ---- prologue: x group 0 -> half 0, B step 0 -> buf 0, then spline step 0 -> A buf 0
  glds16(xgbase, xl);
#pragma unroll
  for (int q = 0; q < 4; ++q)
    glds16(bgbase + (size_t)q * 32 * KDIM, bl + q * 4096);
  asm volatile("s_waitcnt vmcnt(0)" ::: "memory");
  __syncthreads();
  STAGE_A(0, 0);

  for (int s = 0; s < STEPS; ++s) {
    __syncthreads();                 // buf[s&1] (A writes + B DMA) complete for all waves
    const int cur = s & 1;
    // issue next step's async loads NOW; drained by the pre-barrier vmcnt(0) at step end
    if (s + 1 < STEPS) {
#pragma unroll
      for (int q = 0; q < 4; ++q)
        glds16(bgbase + (size_t)(s + 1) * BK + (size_t)q * 32 * KDIM,
               bl + (1 - cur) * 16384 + q * 4096);
    }
    if (((s & 1) == 0) && (s + 2 < STEPS)) {
      const int g = (s >> 1) + 1;    // x group for steps 2g, 2g+1
      glds16(xgbase + g * 8, xl + (g & 1) * 4096);
    }
    // MFMA phase on buf[cur]
    const char* Ac = (const char*)&Ash[0][0] + cur * 16384;
    const char* Bc = (const char*)&Bsh[0][0] + cur * 16384;
    __builtin_amdgcn_s_setprio(1);
#pragma unroll
    for (int kc = 0; kc < 2; ++kc) {
      short8 af[4], bfr[4];
#pragma unroll
      for (int f = 0; f < 4; ++f) af[f] = *(const short8*)(Ac + (aoff[f] ^ (kc << 6)));
#pragma unroll
      for (int f = 0; f < 4; ++f) bfr[f] = *(const short8*)(Bc + (boff[f] ^ (kc << 6)));
#pragma unroll
      for (int mf = 0; mf < 4; ++mf)
#pragma unroll
        for (int nf = 0; nf < 4; ++nf)
          acc[mf][nf] = __builtin_amdgcn_mfma_f32_16x16x32_bf16(af[mf], bfr[nf], acc[mf][nf], 0, 0, 0);
    }
    __builtin_amdgcn_s_setprio(0);
    // spline-stage step s+1 into buf[1-cur]
    if (s + 1 < STEPS) STAGE_A(s + 1, 1 - cur);
  }

  // epilogue: split-K accumulate
#pragma unroll
  for (int mf = 0; mf < 4; ++mf)
#pragma unroll
    for (int nf = 0; nf < 4; ++nf)
#pragma unroll
      for (int q = 0; q < 4; ++q) {
        int row = mb + wm * 64 + mf * 16 + ((lane >> 4) << 2) + q;
        int col = ob + wn * 64 + nf * 16 + (lane & 15);
        atomicAdd(out + (size_t)row * OUT_DIM + col, acc[mf][nf][q]);
      }
}

extern "C" void kernel_launch(void* const* d_in, const int* in_sizes, int n_in,
                              void* d_out, int out_size, void* d_ws, size_t ws_size,
                              hipStream_t stream) {
  const float* x     = (const float*)d_in[0];   // (4,2048,256) f32
  const float* coeff = (const float*)d_in[1];   // (8,13) f32
  const float* gw    = (const float*)d_in[2];   // (256,256,8) f32
  float* out = (float*)d_out;                   // (4,2048,256) f32
  unsigned short* BmT = (unsigned short*)d_ws;  // 256 x 4096 bf16 = 2 MB

  kan_prep<<<dim3(16, 16), dim3(256), 0, stream>>>(coeff, gw, BmT, out);
  dim3 grid(8192 / TM, OUT_DIM / TN, KSPLIT);
  kan_gemm<<<grid, dim3(256), 0, stream>>>(x, BmT, out);
}

// Round 4
// 105.115 us; speedup vs baseline: 1.0859x; 1.0859x over previous
//
#include <hip/hip_runtime.h>

typedef __attribute__((ext_vector_type(8))) short short8;
typedef __attribute__((ext_vector_type(4))) float f32x4;

#define IN_DIM 256
#define OUT_DIM 256
#define NB 16                 // padded basis count (13 real + 3 zero)
#define KDIM (IN_DIM * NB)    // 4096
#define TM 32
#define TN 128
#define BK 128                // 8 i-values per K-step (256 B per row)
#define STEPS (IN_DIM / 8)    // 32 steps, full K per block (no split-K)
#define ABUF (TM * BK * 2)    // bytes per A double-buffer half  (8192)
#define BBUF (TN * BK * 2)    // bytes per B double-buffer half  (32768)

__device__ __forceinline__ unsigned short f2bf(float f) {
  union { float f; unsigned int u; } v; v.f = f;
  unsigned int r = v.u + 0x7fffu + ((v.u >> 16) & 1u);  // RNE
  return (unsigned short)(r >> 16);
}

// async global->LDS, 16 B per lane, linear wave dest (base + lane*16)
__device__ __forceinline__ void glds16(const void* g, void* l) {
  __builtin_amdgcn_global_load_lds((__attribute__((address_space(1))) const void*)g,
                                   (__attribute__((address_space(3))) void*)l, 16, 0, 0);
}

// branchless cubic B-spline row: 16 bf16 slots (packed into d[8] u32), 4 nonzeros at c..c+3
__device__ __forceinline__ void spline_row(float xv, unsigned* d) {
  float xc = fminf(fmaxf(xv, -1.0f), 1.0f - 1e-6f);
  float u = (xc + 1.0f) * 5.0f;            // h = 0.2
  int c = (int)u;
  c = c > 9 ? 9 : (c < 0 ? 0 : c);
  float tt = u - (float)c;
  float omt = 1.0f - tt;
  float t2 = tt * tt, t3 = t2 * tt;
  float b0 = omt * omt * omt * (1.0f / 6.0f);
  float b1 = (3.0f * t3 - 6.0f * t2 + 4.0f) * (1.0f / 6.0f);
  float b2 = (-3.0f * t3 + 3.0f * t2 + 3.0f * tt + 1.0f) * (1.0f / 6.0f);
  float b3 = t3 * (1.0f / 6.0f);
  unsigned h0 = f2bf(b0), h1 = f2bf(b1), h2 = f2bf(b2), h3 = f2bf(b3);
  const int a = c >> 1;
  const bool odd = (c & 1) != 0;
  unsigned p01 = h0 | (h1 << 16);
  unsigned p23 = h2 | (h3 << 16);
  unsigned A0 = odd ? (h0 << 16) : p01;
  unsigned A1 = odd ? (h1 | (h2 << 16)) : p23;
  unsigned A2 = odd ? h3 : 0u;
#pragma unroll
  for (int j = 0; j < 8; ++j) {
    unsigned v = (j == a) ? A0 : 0u;
    v = (j == a + 1) ? A1 : v;
    v = (j == a + 2) ? A2 : v;
    d[j] = v;
  }
}

// --- prep: BmT[o][i*16+n] = bf16( sum_e softmax(gating[i,o,:])[e] * coeff[e,n] )
// (no output zeroing: gemm does plain stores, no atomics)
__global__ __launch_bounds__(256) void kan_prep(const float* __restrict__ coeff,
                                                const float* __restrict__ gw,
                                                unsigned short* __restrict__ BmT) {
  __shared__ float csh[104];
  __shared__ unsigned short tile[16][256];   // [o_loc][il*16+n]
  const int t = threadIdx.x;
  if (t < 104) csh[t] = coeff[t];
  __syncthreads();
  const int otile = blockIdx.x, itile = blockIdx.y;
  const int il = t >> 4, ol = t & 15;
  const int i = itile * 16 + il;
  const int o = otile * 16 + ol;
  const float* g = gw + (size_t)(i * OUT_DIM + o) * 8;
  float4 g0 = *(const float4*)g;
  float4 g1 = *(const float4*)(g + 4);
  float ge[8] = {g0.x, g0.y, g0.z, g0.w, g1.x, g1.y, g1.z, g1.w};
  float mx = ge[0];
#pragma unroll
  for (int e = 1; e < 8; ++e) mx = fmaxf(mx, ge[e]);
  float p[8]; float s = 0.f;
#pragma unroll
  for (int e = 0; e < 8; ++e) { p[e] = __expf(ge[e] - mx); s += p[e]; }
  const float inv = 1.0f / s;
  unsigned short row[16];
#pragma unroll
  for (int n = 0; n < 13; ++n) {
    float w = 0.f;
#pragma unroll
    for (int e = 0; e < 8; ++e) w += p[e] * csh[e * 13 + n];
    row[n] = f2bf(w * inv);
  }
  row[13] = 0; row[14] = 0; row[15] = 0;
  int4* dst = (int4*)&tile[ol][il * 16];
  dst[0] = *(const int4*)&row[0];
  dst[1] = *(const int4*)&row[8];
  __syncthreads();
  const int oo = t >> 4, ck = t & 15;
  int4 v0 = *(const int4*)&tile[oo][ck * 16];
  int4 v1 = *(const int4*)&tile[oo][ck * 16 + 8];
  int4* out4 = (int4*)(BmT + (size_t)(otile * 16 + oo) * KDIM + itile * 256 + ck * 16);
  out4[0] = v0;
  out4[1] = v1;
}

// --- fused basis + GEMM: out[m][o] = sum_k A[m][k] * BmT[o][k], k = i*16+n
// TM=32 x TN=128 tile, FULL K per block -> direct coalesced stores (no atomics,
// no zero pass). 512 blocks, 2/CU. XOR-swizzled unpadded LDS (granule ^= row&7
// within 256 B rows); B staged via global_load_lds with inverse-swizzled per-lane
// source; A staged by in-register spline eval writing straight to swizzled LDS.
// One barrier/step, double-buffered; 80 KiB LDS -> 2 blocks/CU.
__global__ __launch_bounds__(256, 2) void kan_gemm(const float* __restrict__ x,
                                                   const unsigned short* __restrict__ BmT,
                                                   float* __restrict__ out) {
  __shared__ unsigned short Ash[2][TM * BK];   // 2 x 8192 B, swizzled [row][128k]
  __shared__ unsigned short Bsh[2][TN * BK];   // 2 x 32768 B, swizzled [o][128k]

  const int t = threadIdx.x;
  const int lane = t & 63;
  const int wave = t >> 6;                     // 4 waves: 1 M x 4 N, each 32x32
  const int wn = wave;
  const int mb = blockIdx.x * TM;
  const int ob = blockIdx.y * TN;

  // A-stager mapping: thread -> (row r, i-slot il); 1 spline eval / thread / step
  const int r = t & 31;
  const int il = t >> 5;
  const float* xptr = x + (size_t)(mb + r) * IN_DIM + il;   // value for step s at xptr[s*8]
  char* const abase = (char*)&Ash[0][0] + r * 256;
  const int msw = r & 7;
  const int aw0 = ((2 * il + 0) ^ msw) << 4;   // swizzled byte slots for this eval
  const int aw1 = ((2 * il + 1) ^ msw) << 4;

  // B DMA: call q covers LDS linear bytes q*4096 + t*16 of the step tile
  //   row = q*16 + (t>>4); linear granule (t&15) must hold global granule (t&15)^(row&7)
  const unsigned short* bgbase =
      BmT + (size_t)(ob + (t >> 4)) * KDIM + ((t & 15) ^ ((t >> 4) & 7)) * 8;
  char* const bl = (char*)&Bsh[0][0] + wave * 1024;   // wave-uniform dest base

  f32x4 acc[2][2];
#pragma unroll
  for (int a = 0; a < 2; ++a)
#pragma unroll
    for (int b = 0; b < 2; ++b) acc[a][b] = (f32x4){0.f, 0.f, 0.f, 0.f};

  // swizzled fragment read offsets (kc=0); kc toggles via ^(kc<<6)
  int aoff[2], boff[2];
#pragma unroll
  for (int f = 0; f < 2; ++f) {
    const int ro = f * 16 + (lane & 15);
    aoff[f] = ro * 256 + (((lane >> 4) ^ (ro & 7)) << 4);
    const int bo = wn * 32 + f * 16 + (lane & 15);
    boff[f] = bo * 256 + (((lane >> 4) ^ (bo & 7)) << 4);
  }

  // ---- prologue: B step 0 -> buf 0; x step 0 -> reg; spline -> A buf 0
  {
#pragma unroll
    for (int q = 0; q < 8; ++q)
      glds16(bgbase + (size_t)q * 16 * KDIM, bl + q * 4096);
    float xv = *xptr;
    unsigned d[8];
    spline_row(xv, d);
    *(int4*)(abase + aw0) = *(const int4*)&d[0];
    *(int4*)(abase + aw1) = *(const int4*)&d[4];
    asm volatile("s_waitcnt vmcnt(0)" ::: "memory");
  }

  for (int s = 0; s < STEPS; ++s) {
    __syncthreads();                 // buf[s&1] (A writes + B DMA) complete for all waves
    const int cur = s & 1;
    // prefetch next step: x to register FIRST (so its use waits vmcnt(8), not 0),
    // then the 8 B-DMAs into the other buffer (drained by the next barrier).
    float xn = 0.f;
    if (s + 1 < STEPS) {
      xn = xptr[(s + 1) * 8];
#pragma unroll
      for (int q = 0; q < 8; ++q)
        glds16(bgbase + (size_t)(s + 1) * BK + (size_t)q * 16 * KDIM,
               bl + (1 - cur) * BBUF + q * 4096);
    }
    // MFMA phase on buf[cur]
    const char* Ac = (const char*)&Ash[0][0] + cur * ABUF;
    const char* Bc = (const char*)&Bsh[0][0] + cur * BBUF;
    __builtin_amdgcn_s_setprio(1);
#pragma unroll
    for (int kc = 0; kc < 4; ++kc) {
      short8 af[2], bfr[2];
#pragma unroll
      for (int f = 0; f < 2; ++f) af[f] = *(const short8*)(Ac + (aoff[f] ^ (kc << 6)));
#pragma unroll
      for (int f = 0; f < 2; ++f) bfr[f] = *(const short8*)(Bc + (boff[f] ^ (kc << 6)));
#pragma unroll
      for (int mf = 0; mf < 2; ++mf)
#pragma unroll
        for (int nf = 0; nf < 2; ++nf)
          acc[mf][nf] = __builtin_amdgcn_mfma_f32_16x16x32_bf16(af[mf], bfr[nf], acc[mf][nf], 0, 0, 0);
    }
    __builtin_amdgcn_s_setprio(0);
    // spline-stage step s+1 into buf[1-cur]
    if (s + 1 < STEPS) {
      unsigned d[8];
      spline_row(xn, d);
      char* an = abase + (1 - cur) * ABUF;
      *(int4*)(an + aw0) = *(const int4*)&d[0];
      *(int4*)(an + aw1) = *(const int4*)&d[4];
    }
  }

  // epilogue: direct coalesced stores (each output element written exactly once)
#pragma unroll
  for (int mf = 0; mf < 2; ++mf)
#pragma unroll
    for (int nf = 0; nf < 2; ++nf)
#pragma unroll
      for (int q = 0; q < 4; ++q) {
        int row = mb + mf * 16 + ((lane >> 4) << 2) + q;
        int col = ob + wn * 32 + nf * 16 + (lane & 15);
        out[(size_t)row * OUT_DIM + col] = acc[mf][nf][q];
      }
}

extern "C" void kernel_launch(void* const* d_in, const int* in_sizes, int n_in,
                              void* d_out, int out_size, void* d_ws, size_t ws_size,
                              hipStream_t stream) {
  const float* x     = (const float*)d_in[0];   // (4,2048,256) f32
  const float* coeff = (const float*)d_in[1];   // (8,13) f32
  const float* gw    = (const float*)d_in[2];   // (256,256,8) f32
  float* out = (float*)d_out;                   // (4,2048,256) f32
  unsigned short* BmT = (unsigned short*)d_ws;  // 256 x 4096 bf16 = 2 MB

  kan_prep<<<dim3(16, 16), dim3(256), 0, stream>>>(coeff, gw, BmT);
  dim3 grid(8192 / TM, OUT_DIM / TN);
  kan_gemm<<<grid, dim3(256), 0, stream>>>(x, BmT, out);
}